// Round 3
// baseline (16.749 us; speedup 1.0000x reference)
//
#include <hip/hip_runtime.h>
#include <hip/hip_bf16.h>

// loss = sum_{i<n} (1 - prod_{j<len_i} (1 - x[i, y[i,j]])),  n = B/8 = 512.
//
// SINGLE dispatch. One block per row (256 threads, L=200 active).
// Each block: gather + block product reduction -> ws[row] = 1 - prod,
// __threadfence, atomicAdd ticket. Exactly one block out of n consecutive
// tickets satisfies (old & (n-1)) == n-1 for ANY counter start value
// (robust to 0xAA poison / leftover state; n=512 is a power of two).
// That block acquire-fences and sum-reduces ws[0..n) into out[0]
// (overwrite -> no memset dispatch, no init needed).

__global__ void __launch_bounds__(256)
fused_loss_kernel(const float* __restrict__ x,
                  const int* __restrict__ y,
                  const int* __restrict__ lengths,
                  float* __restrict__ out,
                  float* __restrict__ ws,
                  unsigned* __restrict__ cnt,
                  int C, int L, int n) {
    const int row = blockIdx.x;
    const int tid = threadIdx.x;            // 0..255
    const int len = lengths[row];

    float v = 1.0f;
    if (tid < L) {
        const int   idx = y[(long long)row * L + tid];    // coalesced
        const float xv  = x[(long long)row * C + idx];    // gather, always valid
        v = (tid < len) ? (1.0f - xv) : 1.0f;
    }

    // 64-lane multiply reduction
    #pragma unroll
    for (int off = 32; off >= 1; off >>= 1)
        v *= __shfl_xor(v, off, 64);

    __shared__ float wprod[4];
    __shared__ bool  amLast;
    const int wave = tid >> 6;
    if ((tid & 63) == 0) wprod[wave] = v;
    __syncthreads();

    if (tid == 0) {
        ws[row] = 1.0f - (wprod[0] * wprod[1] * wprod[2] * wprod[3]);
        __threadfence();                     // release ws[row] before ticket
        const unsigned old = atomicAdd(cnt, 1u);
        amLast = ((old & (unsigned)(n - 1)) == (unsigned)(n - 1));
    }
    __syncthreads();

    if (amLast) {
        __threadfence();                     // acquire all ws writes
        float s = ws[tid] + ws[tid + 256];   // n=512, 256 threads: 2 each
        #pragma unroll
        for (int off = 32; off >= 1; off >>= 1)
            s += __shfl_xor(s, off, 64);
        __shared__ float wsum[4];
        if ((tid & 63) == 0) wsum[wave] = s;
        __syncthreads();
        if (tid == 0)
            out[0] = wsum[0] + wsum[1] + wsum[2] + wsum[3];  // overwrite
    }
}

extern "C" void kernel_launch(void* const* d_in, const int* in_sizes, int n_in,
                              void* d_out, int out_size, void* d_ws, size_t ws_size,
                              hipStream_t stream) {
    const float* x       = (const float*)d_in[0];
    const int*   y       = (const int*)d_in[1];
    const int*   lengths = (const int*)d_in[2];
    float*       out     = (float*)d_out;

    const int B = in_sizes[2];              // 4096
    const int L = in_sizes[1] / B;          // 200
    const int C = in_sizes[0] / B;          // 50000
    const int n = B / 8;                    // 512 rows used

    float*    ws  = (float*)d_ws;           // ws[0..n): per-row terms
    unsigned* cnt = (unsigned*)((char*)d_ws + (size_t)n * sizeof(float));

    fused_loss_kernel<<<n, 256, 0, stream>>>(x, y, lengths, out, ws, cnt, C, L, n);
}

// Round 4
// 9.582 us; speedup vs baseline: 1.7480x; 1.7480x over previous
//
#include <hip/hip_runtime.h>
#include <hip/hip_bf16.h>

// loss = sum_{i<n} (1 - prod_{j<len_i} (1 - x[i, y[i,j]])),  n = B/8 = 512.
//
// SINGLE dispatch, coherent-atomic completion protocol (no __threadfence:
// R3 showed plain-store + fence is both slow (512x buffer_wbl2) and flaky
// cross-XCD -> absmax 8.0). All cross-block traffic uses agent-scope
// atomics (sc1 path, coherence point = shared level, bypasses per-XCD L2).
//
// 128 blocks x 1024 threads, 4 rows/block, one y-load + one x-gather per
// thread. Block reduces 4 row products -> partial = sum(1 - prod_g).
// tid0: partial -> ws[bid] via atomic EXCHANGE (RMW: return value proves
// completion at the coherence point); ticket fetch_add is made
// data-dependent on the returned old value so the compiler must insert
// the vmcnt wait (release ordering without any cache-wide writeback).
// Exactly one of any 128 consecutive tickets satisfies (old&127)==127,
// for ANY counter start value (poison-proof; no reset needed). That block
// reads the 128 partials with agent-scope atomic loads (coherent) and
// overwrites out[0].

#define NBLOCKS 128
#define NTHREADS 1024

__global__ void __launch_bounds__(NTHREADS)
fused_loss_kernel(const float* __restrict__ x,
                  const int* __restrict__ y,
                  const int* __restrict__ lengths,
                  float* __restrict__ out,
                  float* __restrict__ ws,
                  unsigned* __restrict__ cnt,
                  int C, int L) {
    const int tid = threadIdx.x;
    const int sub = tid >> 8;               // 0..3 : row within block
    const int j   = tid & 255;              // 0..255 : position in row
    const int row = blockIdx.x * 4 + sub;

    const int len = lengths[row];
    float v = 1.0f;
    if (j < L) {
        const int   idx = y[(long long)row * L + j];   // coalesced
        const float xv  = x[(long long)row * C + idx]; // gather, always valid
        v = (j < len) ? (1.0f - xv) : 1.0f;
    }

    // 64-lane multiply reduction
    #pragma unroll
    for (int off = 32; off >= 1; off >>= 1)
        v *= __shfl_xor(v, off, 64);

    __shared__ float wprod[16];
    __shared__ bool  amLast;
    const int wave = tid >> 6;              // 0..15 (4 waves per row-group)
    if ((tid & 63) == 0) wprod[wave] = v;
    __syncthreads();

    if (tid == 0) {
        float partial = 0.0f;
        #pragma unroll
        for (int g = 0; g < 4; ++g) {
            const float p = wprod[4*g] * wprod[4*g+1] * wprod[4*g+2] * wprod[4*g+3];
            partial += 1.0f - p;
        }
        // Coherent RMW write of the partial; its return value proves the
        // write reached the coherence point.
        const float oldw = __hip_atomic_exchange(&ws[blockIdx.x], partial,
                                                 __ATOMIC_RELAXED,
                                                 __HIP_MEMORY_SCOPE_AGENT);
        // Data-dependence: ticket increment depends on oldw, forcing the
        // wave to wait for the exchange before the ticket RMW issues.
        unsigned bump = 1u + (unsigned)(oldw == -1e38f); // always 1
        const unsigned old = __hip_atomic_fetch_add(cnt, bump,
                                                    __ATOMIC_RELAXED,
                                                    __HIP_MEMORY_SCOPE_AGENT);
        amLast = ((old & (NBLOCKS - 1)) == (NBLOCKS - 1));
    }
    __syncthreads();

    if (amLast) {
        float s = 0.0f;
        if (tid < NBLOCKS)
            s = __hip_atomic_load(&ws[tid], __ATOMIC_RELAXED,
                                  __HIP_MEMORY_SCOPE_AGENT);
        #pragma unroll
        for (int off = 32; off >= 1; off >>= 1)
            s += __shfl_xor(s, off, 64);
        __shared__ float wsum[16];
        if ((tid & 63) == 0) wsum[wave] = s;
        __syncthreads();
        if (tid == 0) {
            float t = 0.0f;
            #pragma unroll
            for (int w = 0; w < 16; ++w) t += wsum[w];
            out[0] = t;                      // overwrite; no init needed
        }
    }
}

extern "C" void kernel_launch(void* const* d_in, const int* in_sizes, int n_in,
                              void* d_out, int out_size, void* d_ws, size_t ws_size,
                              hipStream_t stream) {
    const float* x       = (const float*)d_in[0];
    const int*   y       = (const int*)d_in[1];
    const int*   lengths = (const int*)d_in[2];
    float*       out     = (float*)d_out;

    const int B = in_sizes[2];              // 4096
    const int L = in_sizes[1] / B;          // 200
    const int C = in_sizes[0] / B;          // 50000

    float*    ws  = (float*)d_ws;                          // [0..128) partials
    unsigned* cnt = (unsigned*)((char*)d_ws + 1024);       // separate line

    fused_loss_kernel<<<NBLOCKS, NTHREADS, 0, stream>>>(x, y, lengths, out,
                                                        ws, cnt, C, L);
}